// Round 1
// baseline (1482.873 us; speedup 1.0000x reference)
//
#include <hip/hip_runtime.h>

// KohonenSOM distances: out[b][n] = ||x[b] - w[n]||_2
// B=65536, N=4900, D=32 (fp32 in, fp32 out).
// Write-BW-bound: 1.285 GB output, ~205 us floor at 6.3 TB/s.
// Cross term via mfma_f32_16x16x32_f16 (K=32 == D, one MFMA per 16x16 tile);
// x^2 / w^2 in fp32 via LDS. fp16 cross error ~0.01 << 0.214 threshold.

typedef _Float16 half8 __attribute__((ext_vector_type(8)));
typedef float f32x4 __attribute__((ext_vector_type(4)));

#define TILE 128   // block tile (128x128), 4 waves in 2x2, each wave 64x64

__global__ __launch_bounds__(256, 2)
void som_dist(const float* __restrict__ x, const float* __restrict__ w,
              float* __restrict__ out, int B, int N)
{
    __shared__ float sx2[TILE];
    __shared__ float sw2[TILE];

    const int tid     = threadIdx.x;
    const int rowBase = blockIdx.y * TILE;   // B = 65536 divisible by 128
    const int colBase = blockIdx.x * TILE;   // N = 4900: edge predicated

    // ---- cooperative fp32 squared norms into LDS ----
    if (tid < TILE) {
        const float4* p = (const float4*)(x + (size_t)(rowBase + tid) * 32);
        float s = 0.f;
#pragma unroll
        for (int i = 0; i < 8; ++i) {
            float4 v = p[i];
            s += v.x * v.x + v.y * v.y + v.z * v.z + v.w * v.w;
        }
        sx2[tid] = s;
    } else {
        const int c   = tid - TILE;
        const int col = colBase + c;
        float s = 0.f;
        if (col < N) {
            const float4* p = (const float4*)(w + (size_t)col * 32);
#pragma unroll
            for (int i = 0; i < 8; ++i) {
                float4 v = p[i];
                s += v.x * v.x + v.y * v.y + v.z * v.z + v.w * v.w;
            }
        }
        sw2[c] = s;
    }
    __syncthreads();

    const int wave  = tid >> 6;
    const int lane  = tid & 63;
    const int waveR = (wave >> 1) * 64;      // 0 or 64
    const int waveC = (wave & 1) * 64;       // 0 or 64
    const int lr    = lane & 15;             // m (A) / n (B) within 16-tile
    const int ko    = (lane >> 4) * 8;       // k offset: quad*8

    // ---- A fragments: x[row][ko..ko+7], fp32 -> fp16 ----
    half8 af[4];
#pragma unroll
    for (int i = 0; i < 4; ++i) {
        const float* p = x + (size_t)(rowBase + waveR + i * 16 + lr) * 32 + ko;
        const float4 v0 = ((const float4*)p)[0];
        const float4 v1 = ((const float4*)p)[1];
        half8 a;
        a[0] = (_Float16)v0.x; a[1] = (_Float16)v0.y;
        a[2] = (_Float16)v0.z; a[3] = (_Float16)v0.w;
        a[4] = (_Float16)v1.x; a[5] = (_Float16)v1.y;
        a[6] = (_Float16)v1.z; a[7] = (_Float16)v1.w;
        af[i] = a;
    }

    // ---- B fragments: w[col][ko..ko+7] (W stored [n][k] == B^T layout need) ----
    half8 bf[4];
#pragma unroll
    for (int j = 0; j < 4; ++j) {
        const int col = colBase + waveC + j * 16 + lr;
        half8 b;
#pragma unroll
        for (int t = 0; t < 8; ++t) b[t] = (_Float16)0.f;
        if (col < N) {
            const float* p = w + (size_t)col * 32 + ko;
            const float4 v0 = ((const float4*)p)[0];
            const float4 v1 = ((const float4*)p)[1];
            b[0] = (_Float16)v0.x; b[1] = (_Float16)v0.y;
            b[2] = (_Float16)v0.z; b[3] = (_Float16)v0.w;
            b[4] = (_Float16)v1.x; b[5] = (_Float16)v1.y;
            b[6] = (_Float16)v1.z; b[7] = (_Float16)v1.w;
        }
        bf[j] = b;
    }

    // ---- cross terms: one MFMA per 16x16 tile (K = 32 = D) ----
    f32x4 acc[4][4];
#pragma unroll
    for (int i = 0; i < 4; ++i) {
#pragma unroll
        for (int j = 0; j < 4; ++j) {
            f32x4 z = {0.f, 0.f, 0.f, 0.f};
            acc[i][j] = __builtin_amdgcn_mfma_f32_16x16x32_f16(af[i], bf[j], z, 0, 0, 0);
        }
    }

    // ---- epilogue: sqrt(max(x2 + w2 - 2c, 0)) ----
    // C/D layout (16x16): col = lane&15, row = (lane>>4)*4 + reg
    const int erow = (lane >> 4) * 4;
    const int ecol = lane & 15;
#pragma unroll
    for (int i = 0; i < 4; ++i) {
#pragma unroll
        for (int j = 0; j < 4; ++j) {
            const int col_l = waveC + j * 16 + ecol;
            const int col   = colBase + col_l;
            if (col < N) {
                const float w2v = sw2[col_l];
#pragma unroll
                for (int r = 0; r < 4; ++r) {
                    const int row_l = waveR + i * 16 + erow + r;
                    float sq = sx2[row_l] + w2v - 2.0f * acc[i][j][r];
                    sq = fmaxf(sq, 0.0f);
                    out[(size_t)(rowBase + row_l) * N + col] = __builtin_amdgcn_sqrtf(sq);
                }
            }
        }
    }
}

extern "C" void kernel_launch(void* const* d_in, const int* in_sizes, int n_in,
                              void* d_out, int out_size, void* d_ws, size_t ws_size,
                              hipStream_t stream) {
    const float* x   = (const float*)d_in[0];
    const float* w   = (const float*)d_in[1];
    float*       out = (float*)d_out;
    const int B = in_sizes[0] / 32;   // 65536
    const int N = in_sizes[1] / 32;   // 4900
    dim3 grid((N + TILE - 1) / TILE, (B + TILE - 1) / TILE);
    som_dist<<<grid, 256, 0, stream>>>(x, w, out, B, N);
}